// Round 1
// baseline (1131.277 us; speedup 1.0000x reference)
//
#include <hip/hip_runtime.h>

#define NUM_GRAPHS 256

// ---------------- degrees ----------------
__global__ void k_deg(const int* __restrict__ src, const int* __restrict__ dst,
                      int* __restrict__ outdeg, int* __restrict__ indeg, int E) {
    int i = blockIdx.x * 256 + threadIdx.x;
    if (i < E) {
        atomicAdd(&outdeg[src[i]], 1);
        atomicAdd(&indeg[dst[i]], 1);
    }
}

// ---------------- projection: H[n][c] = (X[n,:] . W[:,c]) * rsqrt(max(outdeg,1)) ----------------
// block = 256 threads, covers 256 nodes. K tiled by 32. Each thread: 4 nodes x 4 classes.
// LDS strides: x stride 36 floats, Wt stride 260 floats -> all ds_read_b128 <=2-way conflicts (free).
__global__ __launch_bounds__(256) void k_gemm(const float* __restrict__ X,
                                              const float* __restrict__ W,
                                              const int* __restrict__ outdeg,
                                              float* __restrict__ H, int N) {
    __shared__ __align__(16) float lx[256 * 36];   // 36.9 KB
    __shared__ __align__(16) float lw[16 * 260];   // 16.6 KB (W transposed: [c][k])
    const int t = threadIdx.x;
    const int node0 = blockIdx.x * 256;

    // stage W transposed (full K)
    for (int i = t; i < 256 * 16; i += 256) {
        int k = i >> 4, c = i & 15;
        lw[c * 260 + k] = W[i];
    }

    const int m  = t >> 2;        // 0..63 : node within-wave index
    const int cb = (t & 3) * 4;   // class quad base: 0,4,8,12

    float4 acc[4][4];
#pragma unroll
    for (int j = 0; j < 4; ++j)
#pragma unroll
        for (int ci = 0; ci < 4; ++ci) acc[j][ci] = float4{0.f, 0.f, 0.f, 0.f};

    for (int kt = 0; kt < 8; ++kt) {
        const int k0 = kt * 32;
        __syncthreads();  // previous tile's readers done (also orders lw stage on kt=0)
        // stage x tile: 256 rows x 32 cols
#pragma unroll
        for (int i = 0; i < 8; ++i) {
            int f = t + 256 * i;           // 0..2047
            int row = f >> 3, c4 = f & 7;  // 8 float4 per row
            float4 v = float4{0.f, 0.f, 0.f, 0.f};
            int node = node0 + row;
            if (node < N) v = *(const float4*)&X[(size_t)node * 256 + k0 + c4 * 4];
            *(float4*)&lx[row * 36 + c4 * 4] = v;
        }
        __syncthreads();
#pragma unroll
        for (int kk = 0; kk < 32; kk += 4) {
            float4 wv[4], xv[4];
#pragma unroll
            for (int ci = 0; ci < 4; ++ci)
                wv[ci] = *(const float4*)&lw[(cb + ci) * 260 + k0 + kk];
#pragma unroll
            for (int j = 0; j < 4; ++j)
                xv[j] = *(const float4*)&lx[(m + 64 * j) * 36 + kk];
#pragma unroll
            for (int j = 0; j < 4; ++j)
#pragma unroll
                for (int ci = 0; ci < 4; ++ci) {
                    acc[j][ci].x += xv[j].x * wv[ci].x;
                    acc[j][ci].y += xv[j].y * wv[ci].y;
                    acc[j][ci].z += xv[j].z * wv[ci].z;
                    acc[j][ci].w += xv[j].w * wv[ci].w;
                }
        }
    }

#pragma unroll
    for (int j = 0; j < 4; ++j) {
        int node = node0 + m + 64 * j;
        if (node < N) {
            float norm = rsqrtf(fmaxf((float)outdeg[node], 1.f));
            float4 o;
#pragma unroll
            for (int ci = 0; ci < 4; ++ci) {
                float s = acc[j][ci].x + acc[j][ci].y + acc[j][ci].z + acc[j][ci].w;
                ((float*)&o)[ci] = s * norm;
            }
            *(float4*)&H[(size_t)node * 16 + cb] = o;
        }
    }
}

// ---------------- edge scatter: agg[dst] += H[src] ----------------
// 4 threads per edge, float4 gather + 4 scalar fp32 atomics each.
__global__ void k_scatter(const int* __restrict__ src, const int* __restrict__ dst,
                          const float* __restrict__ H, float* __restrict__ agg, int E) {
    int tid = blockIdx.x * 256 + threadIdx.x;
    int e = tid >> 2;
    if (e < E) {
        int c4 = (tid & 3) * 4;
        int s = src[e], d = dst[e];
        float4 v = *(const float4*)&H[(size_t)s * 16 + c4];
        float* p = &agg[(size_t)d * 16 + c4];
        unsafeAtomicAdd(p + 0, v.x);
        unsafeAtomicAdd(p + 1, v.y);
        unsafeAtomicAdd(p + 2, v.z);
        unsafeAtomicAdd(p + 3, v.w);
    }
}

// ---------------- per-node finalize + per-graph LDS reduction ----------------
// segment_ids sorted => each 256-node block spans few graphs.
__global__ __launch_bounds__(256) void k_greduce(const float* __restrict__ agg,
                                                 const int* __restrict__ indeg,
                                                 const int* __restrict__ seg,
                                                 float* __restrict__ gsum,
                                                 float* __restrict__ gcnt, int N) {
    __shared__ float lg[256 * 16];
    __shared__ float lc[256];
    const int t = threadIdx.x;
    const int bs = blockIdx.x * 256;
    if (bs >= N) return;
    const int gf = seg[bs];
    int last = bs + 255; if (last >= N) last = N - 1;
    const int gl = seg[last];

    for (int i = t; i < 256 * 16; i += 256) lg[i] = 0.f;
    lc[t] = 0.f;
    __syncthreads();

    const int c = t & 15;
#pragma unroll
    for (int p = 0; p < 16; ++p) {
        int idx = bs + p * 16 + (t >> 4);
        if (idx < N) {
            int g = seg[idx];
            float nd = rsqrtf(fmaxf((float)indeg[idx], 1.f));
            float v = agg[(size_t)idx * 16 + c] * nd;
            atomicAdd(&lg[(g - gf) * 16 + c], v);
            if (c == 0) atomicAdd(&lc[g - gf], 1.f);
        }
    }
    __syncthreads();

    const int span = gl - gf + 1;
    for (int i = t; i < span * 16; i += 256)
        unsafeAtomicAdd(&gsum[gf * 16 + i], lg[i]);
    for (int i = t; i < span; i += 256)
        unsafeAtomicAdd(&gcnt[gf + i], lc[i]);
}

// ---------------- final: out = gsum / max(gcnt,1) + b ----------------
__global__ void k_final(const float* __restrict__ gsum, const float* __restrict__ gcnt,
                        const float* __restrict__ b, float* __restrict__ out) {
    int i = blockIdx.x * 256 + threadIdx.x;
    if (i < NUM_GRAPHS * 16) {
        int g = i >> 4, c = i & 15;
        out[i] = gsum[i] / fmaxf(gcnt[g], 1.f) + b[c];
    }
}

extern "C" void kernel_launch(void* const* d_in, const int* in_sizes, int n_in,
                              void* d_out, int out_size, void* d_ws, size_t ws_size,
                              hipStream_t stream) {
    const float* X   = (const float*)d_in[0];
    const float* W   = (const float*)d_in[1];
    const float* b   = (const float*)d_in[2];
    const int* esrc  = (const int*)d_in[3];
    const int* edst  = (const int*)d_in[4];
    const int* seg   = (const int*)d_in[5];
    const int N = in_sizes[5];   // 100000
    const int E = in_sizes[3];   // 3200000

    // ws layout
    float* H      = (float*)d_ws;                 // N*16
    float* agg    = H + (size_t)N * 16;           // N*16
    int*   outdeg = (int*)(agg + (size_t)N * 16); // N
    int*   indeg  = outdeg + N;                   // N
    float* gsum   = (float*)(indeg + N);          // G*16
    float* gcnt   = gsum + NUM_GRAPHS * 16;       // G

    // zero agg..gcnt in one contiguous memset (H needn't be zeroed)
    size_t zero_bytes = (size_t)((char*)(gcnt + NUM_GRAPHS) - (char*)agg);
    hipMemsetAsync(agg, 0, zero_bytes, stream);

    k_deg<<<(E + 255) / 256, 256, 0, stream>>>(esrc, edst, outdeg, indeg, E);
    k_gemm<<<(N + 255) / 256, 256, 0, stream>>>(X, W, outdeg, H, N);
    k_scatter<<<((size_t)E * 4 + 255) / 256, 256, 0, stream>>>(esrc, edst, H, agg, E);
    k_greduce<<<(N + 255) / 256, 256, 0, stream>>>(agg, indeg, seg, gsum, gcnt, N);
    k_final<<<(NUM_GRAPHS * 16 + 255) / 256, 256, 0, stream>>>(gsum, gcnt, b, (float*)d_out);
}

// Round 2
// 815.374 us; speedup vs baseline: 1.3874x; 1.3874x over previous
//
#include <hip/hip_runtime.h>

#define NUM_GRAPHS 256

// ---------------- degree histograms ----------------
__global__ void k_hist(const int* __restrict__ src, const int* __restrict__ dst,
                       int* __restrict__ outdeg, int* __restrict__ indeg, int E) {
    int i = blockIdx.x * 256 + threadIdx.x;
    if (i < E) {
        atomicAdd(&outdeg[src[i]], 1);
        atomicAdd(&indeg[dst[i]], 1);
    }
}

// ---------------- scan phase 1: per-1024-element block sums ----------------
__global__ __launch_bounds__(256) void k_scan1(const int* __restrict__ indeg,
                                               int* __restrict__ bsum, int N) {
    __shared__ int red[256];
    int t = threadIdx.x;
    int base = blockIdx.x * 1024 + t * 4;
    int s = 0;
#pragma unroll
    for (int k = 0; k < 4; ++k) { int i = base + k; if (i < N) s += indeg[i]; }
    red[t] = s; __syncthreads();
    for (int off = 128; off > 0; off >>= 1) {
        if (t < off) red[t] += red[t + off];
        __syncthreads();
    }
    if (t == 0) bsum[blockIdx.x] = red[0];
}

// ---------------- scan phase 2: serial scan of ~98 block sums ----------------
__global__ void k_scan2(const int* __restrict__ bsum, int* __restrict__ bbase,
                        int* __restrict__ offs, int NB, int N) {
    if (threadIdx.x == 0 && blockIdx.x == 0) {
        int run = 0;
        for (int i = 0; i < NB; ++i) { bbase[i] = run; run += bsum[i]; }
        offs[N] = run;
    }
}

// ---------------- scan phase 3: per-element exclusive offsets (+ cursor copy) ----------------
__global__ __launch_bounds__(256) void k_scan3(const int* __restrict__ indeg,
                                               const int* __restrict__ bbase,
                                               int* __restrict__ offs,
                                               int* __restrict__ cursor, int N) {
    __shared__ int sc[256];
    int t = threadIdx.x;
    int base = blockIdx.x * 1024 + t * 4;
    int v[4]; int s = 0;
#pragma unroll
    for (int k = 0; k < 4; ++k) { int i = base + k; v[k] = (i < N) ? indeg[i] : 0; s += v[k]; }
    sc[t] = s; __syncthreads();
    for (int off = 1; off < 256; off <<= 1) {
        int add = (t >= off) ? sc[t - off] : 0;
        __syncthreads();
        sc[t] += add;
        __syncthreads();
    }
    int run = bbase[blockIdx.x] + sc[t] - s;  // exclusive prefix for this thread's first elem
#pragma unroll
    for (int k = 0; k < 4; ++k) {
        int i = base + k;
        if (i < N) { offs[i] = run; cursor[i] = run; run += v[k]; }
    }
}

// ---------------- CSR fill: csr[cursor[dst]++] = src ----------------
__global__ void k_fill(const int* __restrict__ src, const int* __restrict__ dst,
                       int* __restrict__ cursor, int* __restrict__ csr, int E) {
    int e = blockIdx.x * 256 + threadIdx.x;
    if (e < E) {
        int d = dst[e];
        int p = atomicAdd(&cursor[d], 1);
        csr[p] = src[e];
    }
}

// ---------------- projection: H[n][c] = (X[n,:] . W[:,c]) * rsqrt(max(outdeg,1)) ----------------
__global__ __launch_bounds__(256) void k_gemm(const float* __restrict__ X,
                                              const float* __restrict__ W,
                                              const int* __restrict__ outdeg,
                                              float* __restrict__ H, int N) {
    __shared__ __align__(16) float lx[256 * 36];
    __shared__ __align__(16) float lw[16 * 260];
    const int t = threadIdx.x;
    const int node0 = blockIdx.x * 256;

    for (int i = t; i < 256 * 16; i += 256) {
        int k = i >> 4, c = i & 15;
        lw[c * 260 + k] = W[i];
    }

    const int m  = t >> 2;
    const int cb = (t & 3) * 4;

    float4 acc[4][4];
#pragma unroll
    for (int j = 0; j < 4; ++j)
#pragma unroll
        for (int ci = 0; ci < 4; ++ci) acc[j][ci] = float4{0.f, 0.f, 0.f, 0.f};

    for (int kt = 0; kt < 8; ++kt) {
        const int k0 = kt * 32;
        __syncthreads();
#pragma unroll
        for (int i = 0; i < 8; ++i) {
            int f = t + 256 * i;
            int row = f >> 3, c4 = f & 7;
            float4 v = float4{0.f, 0.f, 0.f, 0.f};
            int node = node0 + row;
            if (node < N) v = *(const float4*)&X[(size_t)node * 256 + k0 + c4 * 4];
            *(float4*)&lx[row * 36 + c4 * 4] = v;
        }
        __syncthreads();
#pragma unroll
        for (int kk = 0; kk < 32; kk += 4) {
            float4 wv[4], xv[4];
#pragma unroll
            for (int ci = 0; ci < 4; ++ci)
                wv[ci] = *(const float4*)&lw[(cb + ci) * 260 + k0 + kk];
#pragma unroll
            for (int j = 0; j < 4; ++j)
                xv[j] = *(const float4*)&lx[(m + 64 * j) * 36 + kk];
#pragma unroll
            for (int j = 0; j < 4; ++j)
#pragma unroll
                for (int ci = 0; ci < 4; ++ci) {
                    acc[j][ci].x += xv[j].x * wv[ci].x;
                    acc[j][ci].y += xv[j].y * wv[ci].y;
                    acc[j][ci].z += xv[j].z * wv[ci].z;
                    acc[j][ci].w += xv[j].w * wv[ci].w;
                }
        }
    }

#pragma unroll
    for (int j = 0; j < 4; ++j) {
        int node = node0 + m + 64 * j;
        if (node < N) {
            float norm = rsqrtf(fmaxf((float)outdeg[node], 1.f));
            float4 o;
#pragma unroll
            for (int ci = 0; ci < 4; ++ci) {
                float s = acc[j][ci].x + acc[j][ci].y + acc[j][ci].z + acc[j][ci].w;
                ((float*)&o)[ci] = s * norm;
            }
            *(float4*)&H[(size_t)node * 16 + cb] = o;
        }
    }
}

// ---------------- gather + norm_dst + per-graph mean reduction ----------------
// block = 256 threads -> 64 dst nodes, 4 threads/node (each a float4 class quad).
// No global fp atomics for the aggregation; graph sums via LDS buckets
// (segment_ids sorted -> span per 64 nodes is tiny), ~span*17 global atomics/block.
__global__ __launch_bounds__(256) void k_gather_reduce(
    const int* __restrict__ csr, const int* __restrict__ offs,
    const float* __restrict__ H, const int* __restrict__ seg,
    float* __restrict__ gsum, float* __restrict__ gcnt, int N) {
    __shared__ float lg[256 * 16];
    __shared__ float lc[256];
    const int t = threadIdx.x;
    const int node0 = blockIdx.x * 64;
    if (node0 >= N) return;
    int lastn = node0 + 63; if (lastn >= N) lastn = N - 1;
    const int gf = seg[node0];
    const int gl = seg[lastn];
    const int span = gl - gf + 1;

    for (int i = t; i < span * 16; i += 256) lg[i] = 0.f;
    for (int i = t; i < span; i += 256) lc[i] = 0.f;
    __syncthreads();

    const int n  = node0 + (t >> 2);
    const int cb = (t & 3) * 4;
    if (n < N) {
        const int o0 = offs[n], o1 = offs[n + 1];
        float4 acc = float4{0.f, 0.f, 0.f, 0.f};
        for (int j = o0; j < o1; ++j) {
            int s = csr[j];
            const float4 v = *(const float4*)&H[(size_t)s * 16 + cb];
            acc.x += v.x; acc.y += v.y; acc.z += v.z; acc.w += v.w;
        }
        const float norm = rsqrtf(fmaxf((float)(o1 - o0), 1.f));
        const int g = seg[n] - gf;
        float* p = &lg[g * 16 + cb];
        atomicAdd(p + 0, acc.x * norm);
        atomicAdd(p + 1, acc.y * norm);
        atomicAdd(p + 2, acc.z * norm);
        atomicAdd(p + 3, acc.w * norm);
        if ((t & 3) == 0) atomicAdd(&lc[g], 1.f);
    }
    __syncthreads();

    for (int i = t; i < span * 16; i += 256)
        unsafeAtomicAdd(&gsum[gf * 16 + i], lg[i]);
    for (int i = t; i < span; i += 256)
        unsafeAtomicAdd(&gcnt[gf + i], lc[i]);
}

// ---------------- final: out = gsum / max(gcnt,1) + b ----------------
__global__ void k_final(const float* __restrict__ gsum, const float* __restrict__ gcnt,
                        const float* __restrict__ b, float* __restrict__ out) {
    int i = blockIdx.x * 256 + threadIdx.x;
    if (i < NUM_GRAPHS * 16) {
        int g = i >> 4, c = i & 15;
        out[i] = gsum[i] / fmaxf(gcnt[g], 1.f) + b[c];
    }
}

extern "C" void kernel_launch(void* const* d_in, const int* in_sizes, int n_in,
                              void* d_out, int out_size, void* d_ws, size_t ws_size,
                              hipStream_t stream) {
    const float* X  = (const float*)d_in[0];
    const float* W  = (const float*)d_in[1];
    const float* b  = (const float*)d_in[2];
    const int* esrc = (const int*)d_in[3];
    const int* edst = (const int*)d_in[4];
    const int* seg  = (const int*)d_in[5];
    const int N = in_sizes[5];   // 100000
    const int E = in_sizes[3];   // 3200000
    const int NB = (N + 1023) / 1024;  // scan blocks

    // ws layout
    float* H      = (float*)d_ws;                      // N*16 floats
    int*   csr    = (int*)(H + (size_t)N * 16);        // E
    int*   offs   = csr + (size_t)E;                   // N+1
    int*   cursor = offs + (N + 1);                    // N
    int*   bsum   = cursor + N;                        // NB (<=128)
    int*   bbase  = bsum + 128;                        // NB
    int*   outdeg = bbase + 128;                       // N   <- zeroed from here
    int*   indeg  = outdeg + N;                        // N
    float* gsum   = (float*)(indeg + N);               // G*16
    float* gcnt   = gsum + NUM_GRAPHS * 16;            // G

    size_t zero_bytes = (size_t)((char*)(gcnt + NUM_GRAPHS) - (char*)outdeg);
    hipMemsetAsync(outdeg, 0, zero_bytes, stream);

    k_hist <<<(E + 255) / 256, 256, 0, stream>>>(esrc, edst, outdeg, indeg, E);
    k_scan1<<<NB, 256, 0, stream>>>(indeg, bsum, N);
    k_scan2<<<1, 64, 0, stream>>>(bsum, bbase, offs, NB, N);
    k_scan3<<<NB, 256, 0, stream>>>(indeg, bbase, offs, cursor, N);
    k_fill <<<(E + 255) / 256, 256, 0, stream>>>(esrc, edst, cursor, csr, E);
    k_gemm <<<(N + 255) / 256, 256, 0, stream>>>(X, W, outdeg, H, N);
    k_gather_reduce<<<(N + 63) / 64, 256, 0, stream>>>(csr, offs, H, seg, gsum, gcnt, N);
    k_final<<<(NUM_GRAPHS * 16 + 255) / 256, 256, 0, stream>>>(gsum, gcnt, b, (float*)d_out);
}

// Round 3
// 763.500 us; speedup vs baseline: 1.4817x; 1.0679x over previous
//
#include <hip/hip_runtime.h>

#define NUM_GRAPHS 256
#define NB_E 768   // persistent blocks for the edge kernel

// ---------------- degree histograms (6.4M non-returning int atomics) ----------------
__global__ void k_hist(const int* __restrict__ src, const int* __restrict__ dst,
                       int* __restrict__ outdeg, int* __restrict__ indeg, int E) {
    int i = blockIdx.x * 256 + threadIdx.x;
    if (i < E) {
        atomicAdd(&outdeg[src[i]], 1);
        atomicAdd(&indeg[dst[i]], 1);
    }
}

// ---------------- nodes-per-graph count (seg sorted -> LDS buckets) ----------------
__global__ __launch_bounds__(256) void k_gcnt(const int* __restrict__ seg,
                                              int* __restrict__ gcnt, int N) {
    __shared__ int lc[256];
    const int base = blockIdx.x * 1024;
    if (base >= N) return;
    int last = base + 1023; if (last >= N) last = N - 1;
    const int gf = seg[base], gl = seg[last];
    const int span = gl - gf + 1;
    const int t = threadIdx.x;
    for (int i = t; i < span; i += 256) lc[i] = 0;
    __syncthreads();
#pragma unroll
    for (int k = 0; k < 4; ++k) {
        int n = base + k * 256 + t;
        if (n <= last) atomicAdd(&lc[seg[n] - gf], 1);
    }
    __syncthreads();
    for (int i = t; i < span; i += 256) atomicAdd(&gcnt[gf + i], lc[i]);
}

// ---------------- projection: H[n][c] = (X[n,:] . W[:,c]) * rsqrt(max(outdeg,1)) ----------------
__global__ __launch_bounds__(256) void k_gemm(const float* __restrict__ X,
                                              const float* __restrict__ W,
                                              const int* __restrict__ outdeg,
                                              float* __restrict__ H, int N) {
    __shared__ __align__(16) float lx[256 * 36];
    __shared__ __align__(16) float lw[16 * 260];
    const int t = threadIdx.x;
    const int node0 = blockIdx.x * 256;

    for (int i = t; i < 256 * 16; i += 256) {
        int k = i >> 4, c = i & 15;
        lw[c * 260 + k] = W[i];
    }

    const int m  = t >> 2;
    const int cb = (t & 3) * 4;

    float4 acc[4][4];
#pragma unroll
    for (int j = 0; j < 4; ++j)
#pragma unroll
        for (int ci = 0; ci < 4; ++ci) acc[j][ci] = float4{0.f, 0.f, 0.f, 0.f};

    for (int kt = 0; kt < 8; ++kt) {
        const int k0 = kt * 32;
        __syncthreads();
#pragma unroll
        for (int i = 0; i < 8; ++i) {
            int f = t + 256 * i;
            int row = f >> 3, c4 = f & 7;
            float4 v = float4{0.f, 0.f, 0.f, 0.f};
            int node = node0 + row;
            if (node < N) v = *(const float4*)&X[(size_t)node * 256 + k0 + c4 * 4];
            *(float4*)&lx[row * 36 + c4 * 4] = v;
        }
        __syncthreads();
#pragma unroll
        for (int kk = 0; kk < 32; kk += 4) {
            float4 wv[4], xv[4];
#pragma unroll
            for (int ci = 0; ci < 4; ++ci)
                wv[ci] = *(const float4*)&lw[(cb + ci) * 260 + k0 + kk];
#pragma unroll
            for (int j = 0; j < 4; ++j)
                xv[j] = *(const float4*)&lx[(m + 64 * j) * 36 + kk];
#pragma unroll
            for (int j = 0; j < 4; ++j)
#pragma unroll
                for (int ci = 0; ci < 4; ++ci) {
                    acc[j][ci].x += xv[j].x * wv[ci].x;
                    acc[j][ci].y += xv[j].y * wv[ci].y;
                    acc[j][ci].z += xv[j].z * wv[ci].z;
                    acc[j][ci].w += xv[j].w * wv[ci].w;
                }
        }
    }

#pragma unroll
    for (int j = 0; j < 4; ++j) {
        int node = node0 + m + 64 * j;
        if (node < N) {
            float norm = rsqrtf(fmaxf((float)outdeg[node], 1.f));
            float4 o;
#pragma unroll
            for (int ci = 0; ci < 4; ++ci) {
                float s = acc[j][ci].x + acc[j][ci].y + acc[j][ci].z + acc[j][ci].w;
                ((float*)&o)[ci] = s * norm;
            }
            *(float4*)&H[(size_t)node * 16 + cb] = o;
        }
    }
}

// ---------------- edge-level graph accumulation ----------------
// 4 lanes per edge (one float4 class-quad each). Per-block 256x16 graph
// histogram in LDS (stride 17 floats so random-graph atomics spread over all
// 32 banks). Flush = plain coalesced stores to parts[block][4096].
__global__ __launch_bounds__(256) void k_edge(const int* __restrict__ src,
                                              const int* __restrict__ dst,
                                              const int* __restrict__ indeg,
                                              const int* __restrict__ seg,
                                              const float* __restrict__ H,
                                              float* __restrict__ parts, int E) {
    __shared__ float lh[256 * 17];
    const int t = threadIdx.x;
    for (int i = t; i < 256 * 17; i += 256) lh[i] = 0.f;
    __syncthreads();

    const int cb = (t & 3) * 4;
    const int E4 = E * 4;
    for (int idx = blockIdx.x * 256 + t; idx < E4; idx += NB_E * 256) {
        const int e = idx >> 2;
        const int s = src[e];
        const int d = dst[e];
        const float nd = rsqrtf(fmaxf((float)indeg[d], 1.f));
        const int g = seg[d];
        const float4 v = *(const float4*)&H[(size_t)s * 16 + cb];
        float* p = &lh[g * 17 + cb];
        atomicAdd(p + 0, v.x * nd);
        atomicAdd(p + 1, v.y * nd);
        atomicAdd(p + 2, v.z * nd);
        atomicAdd(p + 3, v.w * nd);
    }
    __syncthreads();

    float* pp = &parts[(size_t)blockIdx.x * 4096];
    for (int i = t; i < 4096; i += 256) pp[i] = lh[(i >> 4) * 17 + (i & 15)];
}

// ---------------- reduce parts + /gcnt + bias, write output ----------------
// one block per graph; 16 k-chunks x 16 classes per block.
__global__ __launch_bounds__(256) void k_bfinal(const float* __restrict__ parts,
                                                const int* __restrict__ gcnt,
                                                const float* __restrict__ b,
                                                float* __restrict__ out) {
    __shared__ float red[256];
    const int g = blockIdx.x;
    const int t = threadIdx.x;
    const int c = t & 15, chunk = t >> 4;
    float s = 0.f;
    for (int k = chunk; k < NB_E; k += 16)
        s += parts[(size_t)k * 4096 + g * 16 + c];
    red[t] = s;
    __syncthreads();
    for (int off = 128; off >= 16; off >>= 1) {
        if (t < off) red[t] += red[t + off];
        __syncthreads();
    }
    if (t < 16)
        out[g * 16 + t] = red[t] / fmaxf((float)gcnt[g], 1.f) + b[t];
}

extern "C" void kernel_launch(void* const* d_in, const int* in_sizes, int n_in,
                              void* d_out, int out_size, void* d_ws, size_t ws_size,
                              hipStream_t stream) {
    const float* X  = (const float*)d_in[0];
    const float* W  = (const float*)d_in[1];
    const float* b  = (const float*)d_in[2];
    const int* esrc = (const int*)d_in[3];
    const int* edst = (const int*)d_in[4];
    const int* seg  = (const int*)d_in[5];
    const int N = in_sizes[5];   // 100000
    const int E = in_sizes[3];   // 3200000

    // ws layout (~19.8 MB)
    float* H      = (float*)d_ws;                          // N*16 floats
    float* parts  = H + (size_t)N * 16;                    // NB_E*4096 floats
    int*   outdeg = (int*)(parts + (size_t)NB_E * 4096);   // N   <- zeroed from here
    int*   indeg  = outdeg + N;                            // N
    int*   gcnt   = indeg + N;                             // NUM_GRAPHS

    hipMemsetAsync(outdeg, 0, (size_t)(2 * N + NUM_GRAPHS) * sizeof(int), stream);

    k_hist  <<<(E + 255) / 256, 256, 0, stream>>>(esrc, edst, outdeg, indeg, E);
    k_gcnt  <<<(N + 1023) / 1024, 256, 0, stream>>>(seg, gcnt, N);
    k_gemm  <<<(N + 255) / 256, 256, 0, stream>>>(X, W, outdeg, H, N);
    k_edge  <<<NB_E, 256, 0, stream>>>(esrc, edst, indeg, seg, H, parts, E);
    k_bfinal<<<NUM_GRAPHS, 256, 0, stream>>>(parts, gcnt, b, (float*)d_out);
}

// Round 4
// 723.964 us; speedup vs baseline: 1.5626x; 1.0546x over previous
//
#include <hip/hip_runtime.h>
#include <hip/hip_fp16.h>

#define NUM_GRAPHS 256
#define NSHARD 8

__device__ __forceinline__ unsigned short f2bf(float x) {   // RNE
    unsigned u = __float_as_uint(x);
    u += 0x7FFF + ((u >> 16) & 1);
    return (unsigned short)(u >> 16);
}
__device__ __forceinline__ float bf2f(unsigned short v) {
    return __uint_as_float(((unsigned)v) << 16);
}

// ---------------- sharded degree histograms ----------------
// shard = blockIdx&7 (~XCD round-robin): 8x less same-line atomic contention.
__global__ void k_hist(const int* __restrict__ src, const int* __restrict__ dst,
                       int* __restrict__ shards, int E, int N) {
    int i = blockIdx.x * 256 + threadIdx.x;
    if (i < E) {
        int* sh = shards + (size_t)(blockIdx.x & (NSHARD - 1)) * 2 * N;
        atomicAdd(&sh[src[i]], 1);
        atomicAdd(&sh[N + dst[i]], 1);
    }
}

// ---------------- fold shards -> ns[] (for gemm), pk[] (for edge), gcnt ----------------
// pk[n] = f16bits(rsqrt(max(indeg,1)))<<16 | seg[n]   (one 4B random load in k_edge)
__global__ __launch_bounds__(256) void k_reduce(const int* __restrict__ shards,
                                                const int* __restrict__ seg,
                                                float* __restrict__ ns,
                                                unsigned* __restrict__ pk,
                                                int* __restrict__ gcnt, int N) {
    __shared__ int lc[256];
    const int t = threadIdx.x;
    const int base = blockIdx.x * 1024;
    if (base >= N) return;
    int last = base + 1023; if (last >= N) last = N - 1;
    const int gf = seg[base], gl = seg[last];
    const int span = gl - gf + 1;
    for (int i = t; i < span; i += 256) lc[i] = 0;
    __syncthreads();
#pragma unroll
    for (int k = 0; k < 4; ++k) {
        int n = base + k * 256 + t;
        if (n < N) {
            int od = 0, idg = 0;
#pragma unroll
            for (int s = 0; s < NSHARD; ++s) {
                od  += shards[(size_t)s * 2 * N + n];
                idg += shards[(size_t)s * 2 * N + N + n];
            }
            ns[n] = rsqrtf(fmaxf((float)od, 1.f));
            float nd = rsqrtf(fmaxf((float)idg, 1.f));
            int g = seg[n];
            unsigned hb = (unsigned)__half_as_ushort(__float2half_rn(nd));
            pk[n] = (hb << 16) | (unsigned)g;
            atomicAdd(&lc[g - gf], 1);
        }
    }
    __syncthreads();
    for (int i = t; i < span; i += 256) atomicAdd(&gcnt[gf + i], lc[i]);
}

// ---------------- projection: Hb[n][c] = bf16((X[n,:].W[:,c]) * ns[n]) ----------------
__global__ __launch_bounds__(256) void k_gemm(const float* __restrict__ X,
                                              const float* __restrict__ W,
                                              const float* __restrict__ ns,
                                              unsigned short* __restrict__ Hb, int N) {
    __shared__ __align__(16) float lx[256 * 36];
    __shared__ __align__(16) float lw[16 * 260];
    const int t = threadIdx.x;
    const int node0 = blockIdx.x * 256;

    for (int i = t; i < 256 * 16; i += 256) {
        int k = i >> 4, c = i & 15;
        lw[c * 260 + k] = W[i];
    }

    const int m  = t >> 2;
    const int cb = (t & 3) * 4;

    float4 acc[4][4];
#pragma unroll
    for (int j = 0; j < 4; ++j)
#pragma unroll
        for (int ci = 0; ci < 4; ++ci) acc[j][ci] = float4{0.f, 0.f, 0.f, 0.f};

    for (int kt = 0; kt < 8; ++kt) {
        const int k0 = kt * 32;
        __syncthreads();
#pragma unroll
        for (int i = 0; i < 8; ++i) {
            int f = t + 256 * i;
            int row = f >> 3, c4 = f & 7;
            float4 v = float4{0.f, 0.f, 0.f, 0.f};
            int node = node0 + row;
            if (node < N) v = *(const float4*)&X[(size_t)node * 256 + k0 + c4 * 4];
            *(float4*)&lx[row * 36 + c4 * 4] = v;
        }
        __syncthreads();
#pragma unroll
        for (int kk = 0; kk < 32; kk += 4) {
            float4 wv[4], xv[4];
#pragma unroll
            for (int ci = 0; ci < 4; ++ci)
                wv[ci] = *(const float4*)&lw[(cb + ci) * 260 + k0 + kk];
#pragma unroll
            for (int j = 0; j < 4; ++j)
                xv[j] = *(const float4*)&lx[(m + 64 * j) * 36 + kk];
#pragma unroll
            for (int j = 0; j < 4; ++j)
#pragma unroll
                for (int ci = 0; ci < 4; ++ci) {
                    acc[j][ci].x += xv[j].x * wv[ci].x;
                    acc[j][ci].y += xv[j].y * wv[ci].y;
                    acc[j][ci].z += xv[j].z * wv[ci].z;
                    acc[j][ci].w += xv[j].w * wv[ci].w;
                }
        }
    }

#pragma unroll
    for (int j = 0; j < 4; ++j) {
        int node = node0 + m + 64 * j;
        if (node < N) {
            float norm = ns[node];
            ushort4 o;
            {
                float s0 = acc[j][0].x + acc[j][0].y + acc[j][0].z + acc[j][0].w;
                float s1 = acc[j][1].x + acc[j][1].y + acc[j][1].z + acc[j][1].w;
                float s2 = acc[j][2].x + acc[j][2].y + acc[j][2].z + acc[j][2].w;
                float s3 = acc[j][3].x + acc[j][3].y + acc[j][3].z + acc[j][3].w;
                o.x = f2bf(s0 * norm); o.y = f2bf(s1 * norm);
                o.z = f2bf(s2 * norm); o.w = f2bf(s3 * norm);
            }
            *(ushort4*)&Hb[(size_t)node * 16 + cb] = o;  // 8B aligned
        }
    }
}

// ---------------- edge-level graph accumulation (lane-per-edge) ----------------
// 512 threads/block; per-block 256x16 LDS graph histogram (row stride 17:
// 17 odd -> 17g mod 32 spreads random g over all banks). One packed 4B random
// load for (norm_dst, graph); Hb row = 32B (two dwordx4), L2-resident (3.2MB).
__global__ __launch_bounds__(512) void k_edge(const int* __restrict__ src,
                                              const int* __restrict__ dst,
                                              const unsigned* __restrict__ pk,
                                              const unsigned short* __restrict__ Hb,
                                              float* __restrict__ parts,
                                              int E, int NB) {
    __shared__ float lh[256 * 17];
    const int t = threadIdx.x;
    for (int i = t; i < 256 * 17; i += 512) lh[i] = 0.f;
    __syncthreads();

    for (int e = blockIdx.x * 512 + t; e < E; e += NB * 512) {
        const int s = src[e];
        const int d = dst[e];
        const unsigned p = pk[d];
        const float nd = __half2float(__ushort_as_half((unsigned short)(p >> 16)));
        const int g = (int)(p & 0xFFFFu);
        const uint4* hp = (const uint4*)&Hb[(size_t)s * 16];
        const uint4 h0 = hp[0];
        const uint4 h1 = hp[1];
        float* lp = &lh[g * 17];
        atomicAdd(lp + 0,  bf2f((unsigned short)(h0.x       )) * nd);
        atomicAdd(lp + 1,  bf2f((unsigned short)(h0.x >> 16 )) * nd);
        atomicAdd(lp + 2,  bf2f((unsigned short)(h0.y       )) * nd);
        atomicAdd(lp + 3,  bf2f((unsigned short)(h0.y >> 16 )) * nd);
        atomicAdd(lp + 4,  bf2f((unsigned short)(h0.z       )) * nd);
        atomicAdd(lp + 5,  bf2f((unsigned short)(h0.z >> 16 )) * nd);
        atomicAdd(lp + 6,  bf2f((unsigned short)(h0.w       )) * nd);
        atomicAdd(lp + 7,  bf2f((unsigned short)(h0.w >> 16 )) * nd);
        atomicAdd(lp + 8,  bf2f((unsigned short)(h1.x       )) * nd);
        atomicAdd(lp + 9,  bf2f((unsigned short)(h1.x >> 16 )) * nd);
        atomicAdd(lp + 10, bf2f((unsigned short)(h1.y       )) * nd);
        atomicAdd(lp + 11, bf2f((unsigned short)(h1.y >> 16 )) * nd);
        atomicAdd(lp + 12, bf2f((unsigned short)(h1.z       )) * nd);
        atomicAdd(lp + 13, bf2f((unsigned short)(h1.z >> 16 )) * nd);
        atomicAdd(lp + 14, bf2f((unsigned short)(h1.w       )) * nd);
        atomicAdd(lp + 15, bf2f((unsigned short)(h1.w >> 16 )) * nd);
    }
    __syncthreads();

    float* pp = &parts[(size_t)blockIdx.x * 4096];
    for (int i = t; i < 4096; i += 512) pp[i] = lh[(i >> 4) * 17 + (i & 15)];
}

// ---------------- reduce parts + /gcnt + bias ----------------
__global__ __launch_bounds__(256) void k_bfinal(const float* __restrict__ parts,
                                                const int* __restrict__ gcnt,
                                                const float* __restrict__ b,
                                                float* __restrict__ out, int NB) {
    __shared__ float red[256];
    const int g = blockIdx.x;
    const int t = threadIdx.x;
    const int c = t & 15, chunk = t >> 4;
    float s = 0.f;
    for (int k = chunk; k < NB; k += 16)
        s += parts[(size_t)k * 4096 + g * 16 + c];
    red[t] = s;
    __syncthreads();
    for (int off = 128; off >= 16; off >>= 1) {
        if (t < off) red[t] += red[t + off];
        __syncthreads();
    }
    if (t < 16)
        out[g * 16 + t] = red[t] / fmaxf((float)gcnt[g], 1.f) + b[t];
}

extern "C" void kernel_launch(void* const* d_in, const int* in_sizes, int n_in,
                              void* d_out, int out_size, void* d_ws, size_t ws_size,
                              hipStream_t stream) {
    const float* X  = (const float*)d_in[0];
    const float* W  = (const float*)d_in[1];
    const float* b  = (const float*)d_in[2];
    const int* esrc = (const int*)d_in[3];
    const int* edst = (const int*)d_in[4];
    const int* seg  = (const int*)d_in[5];
    const int N = in_sizes[5];   // 100000
    const int E = in_sizes[3];   // 3200000

    // ws layout: fixed part ~10.4 MB, then parts[NB][4096] sized from ws_size
    unsigned short* Hb = (unsigned short*)d_ws;            // N*16 bf16 (3.2 MB)
    int* shards  = (int*)(Hb + (size_t)N * 16);            // 8*2N ints  <- zeroed
    int* gcnt    = shards + (size_t)NSHARD * 2 * N;        // 256        <- zeroed
    float* ns    = (float*)(gcnt + NUM_GRAPHS);            // N
    unsigned* pk = (unsigned*)(ns + N);                    // N
    float* parts = (float*)(pk + N);                       // NB*4096
    size_t fixed = (size_t)((char*)parts - (char*)d_ws);
    size_t avail = (ws_size > fixed) ? (ws_size - fixed) : 0;
    int NB = (int)(avail / (4096 * sizeof(float)));
    if (NB > 1024) NB = 1024;   // 4 blocks/CU x 8 waves = 32 waves/CU (LDS 70KB/CU)
    if (NB < 64)   NB = 64;     // ws proven >=21MB in earlier rounds; never expected

    hipMemsetAsync(shards, 0, ((size_t)NSHARD * 2 * N + NUM_GRAPHS) * sizeof(int), stream);

    k_hist  <<<(E + 255) / 256, 256, 0, stream>>>(esrc, edst, shards, E, N);
    k_reduce<<<(N + 1023) / 1024, 256, 0, stream>>>(shards, seg, ns, pk, gcnt, N);
    k_gemm  <<<(N + 255) / 256, 256, 0, stream>>>(X, W, ns, Hb, N);
    k_edge  <<<NB, 512, 0, stream>>>(esrc, edst, pk, Hb, parts, E, NB);
    k_bfinal<<<NUM_GRAPHS, 256, 0, stream>>>(parts, gcnt, b, (float*)d_out, NB);
}